// Round 7
// baseline (11124.911 us; speedup 1.0000x reference)
//
#include <hip/hip_runtime.h>
#include <hip/hip_bf16.h>

// TrueMarkovChain v7: v6 structure (8 groups x 32 WGs, group=bid&7, slot=bid>>3)
// + same-XCD fast path for activations:
//   producers double-store acts (plain -> producer L2, sc0sc1 -> L3) and flags
//   encode (t<<3)|XCC_ID. Consumers pick per-slot fast (sc0, local-L2) or slow
//   (sc0sc1, L3) staging based on producer XCD == own XCD. Placement-independent
//   correctness (slow path is the v6-proven one); round-robin placement gives
//   ~100% fast path. Async-stage split overlaps act burst with weight ring.
//   Guarded polls + dead-switch (no hang). xc kernel rewritten for occupancy.

typedef __bf16 v8bf __attribute__((ext_vector_type(8)));
typedef float f32x4 __attribute__((ext_vector_type(4)));
typedef unsigned u32x4 __attribute__((ext_vector_type(4)));

__device__ inline f32x4 mfma16(v8bf a, v8bf b, f32x4 c) {
  return __builtin_amdgcn_mfma_f32_16x16x32_bf16(a, b, c, 0, 0, 0);
}
__device__ inline float silu_f(float x) { return x / (1.f + __expf(-x)); }
__device__ inline v8bf as8(f32x4 x) { union { f32x4 f; v8bf b; } u; u.f = x; return u.b; }
__device__ inline v8bf cvt8(float4 a, float4 b) {
  v8bf v;
  v[0] = (__bf16)a.x; v[1] = (__bf16)a.y; v[2] = (__bf16)a.z; v[3] = (__bf16)a.w;
  v[4] = (__bf16)b.x; v[5] = (__bf16)b.y; v[6] = (__bf16)b.z; v[7] = (__bf16)b.w;
  return v;
}
__device__ inline unsigned bfb(float v) {
  __bf16 b = (__bf16)v; unsigned short u; __builtin_memcpy(&u, &b, 2); return (unsigned)u;
}

#define CLOADP(dst, base, boff)                                        \
  asm volatile("global_load_dwordx4 %0, %1, off offset:%2"             \
               : "=v"(dst) : "v"(base), "n"(boff))

template <int N> __device__ inline void vwait() {
  asm volatile("s_waitcnt vmcnt(%0)" :: "n"(N) : "memory");
  __builtin_amdgcn_sched_barrier(0);
}
__device__ inline void vwait_n(int n) {
  switch (n) {
    case 0: vwait<0>(); break;   case 1: vwait<1>(); break;
    case 2: vwait<2>(); break;   case 3: vwait<3>(); break;
    case 4: vwait<4>(); break;   case 5: vwait<5>(); break;
    case 6: vwait<6>(); break;   case 7: vwait<7>(); break;
    case 8: vwait<8>(); break;   case 9: vwait<9>(); break;
    case 10: vwait<10>(); break; default: vwait<11>(); break;
  }
}

// dual act store: plain (producer L2) + sc0sc1 (L3)
__device__ inline void st16d(__bf16* pf, __bf16* ps, float v) {
  unsigned u = bfb(v);
  asm volatile("global_store_short %0, %2, off\n\t"
               "global_store_short %1, %2, off sc0 sc1"
               :: "v"(pf), "v"(ps), "v"(u) : "memory");
}

// release: drain all WG stores, then dual flag store (plain + sc0sc1)
__device__ inline void release_dual(unsigned* fF, unsigned* fS, int slot, unsigned val) {
  asm volatile("s_waitcnt vmcnt(0)" ::: "memory");
  __syncthreads();
  if (threadIdx.x == 0) {
    asm volatile("global_store_dword %0, %2, off\n\t"
                 "global_store_dword %1, %2, off sc0 sc1"
                 :: "v"(fF + slot), "v"(fS + slot), "v"(val) : "memory");
  }
}

// poll 32 flags (fast+slow), build per-slot fast-select mask
__device__ inline unsigned poll_sel(const unsigned* fF, const unsigned* fS,
                                    unsigned tgt, int myxcd,
                                    unsigned* s_sel, int* s_dead) {
  const int tid = threadIdx.x;
  if (tid == 0) *s_sel = 0u;
  __syncthreads();
  if (tid < 8 && *s_dead == 0) {
    u32x4 vf, vs;
    int guard = 0;
    while (true) {
      asm volatile("global_load_dwordx4 %0, %2, off sc0\n\t"
                   "global_load_dwordx4 %1, %3, off sc0 sc1\n\t"
                   "s_waitcnt vmcnt(0)"
                   : "=v"(vf), "=v"(vs)
                   : "v"(fF + tid * 4), "v"(fS + tid * 4) : "memory");
      bool ok = true;
#pragma unroll
      for (int k = 0; k < 4; ++k) {
        unsigned v = vf[k] > vs[k] ? vf[k] : vs[k];
        ok = ok && ((v >> 3) >= tgt);
      }
      if (ok) break;
      if (++guard > (1 << 18)) { *s_dead = 1; break; }
      __builtin_amdgcn_s_sleep(1);
    }
    unsigned nib = 0;
#pragma unroll
    for (int k = 0; k < 4; ++k) {
      unsigned v = vf[k] > vs[k] ? vf[k] : vs[k];
      if ((v & 7u) == (unsigned)myxcd) nib |= (1u << k);
    }
    atomicOr(s_sel, nib << (tid * 4));
  }
  __syncthreads();
  return *s_sel;
}

// ---------------- fp32 -> bf16 strided converter -----------------------------
__global__ void cvt_kernel(const float* __restrict__ src, __bf16* __restrict__ dst,
                           int total8, int log2cols, int sstride, int soff) {
  int i = blockIdx.x * 256 + threadIdx.x;
  if (i >= total8) return;
  long long e = (long long)i * 8;
  int r = (int)(e >> log2cols);
  int c = (int)(e & ((1LL << log2cols) - 1));
  const float* s = src + (size_t)r * sstride + soff + c;
  float4 f0 = *(const float4*)(s);
  float4 f1 = *(const float4*)(s + 4);
  *(v8bf*)(dst + e) = cvt8(f0, f1);
}

// ---------------- xc[b][t] = x_t @ Wt1x^T + bt1 (occupancy-fixed) ------------
__global__ __launch_bounds__(512, 1) void xc_gemm_kernel(
    const float* __restrict__ past, const __bf16* __restrict__ w1x,
    const float* __restrict__ bt1, __bf16* __restrict__ xc) {
  const int t = blockIdx.z + 1;           // 1..511
  const int mh = blockIdx.y;              // 0..1 (64-row half)
  const int nb = blockIdx.x;              // 0..3 (512-col slice)
  const int tid = threadIdx.x, wid = tid >> 6, lane = tid & 63;
  const int wm = wid >> 2, wn = wid & 3;  // 2 x 4 waves
  const int m0 = mh * 64 + wm * 32;
  const int n0 = nb * 512 + wn * 128;
  const int lr = lane & 15, lc = lane >> 4;
  f32x4 acc[2][8] = {};
  const float* a0p = past + ((size_t)(m0 + lr) * 512 + t) * 1024 + lc * 8;
  const float* a1p = a0p + (size_t)16 * 512 * 1024;
  const __bf16* bp = w1x + (size_t)(n0 + lr) * 1024 + lc * 8;
#pragma unroll 4
  for (int k = 0; k < 1024; k += 32) {
    float4 x00 = *(const float4*)(a0p + k);
    float4 x01 = *(const float4*)(a0p + k + 4);
    float4 x10 = *(const float4*)(a1p + k);
    float4 x11 = *(const float4*)(a1p + k + 4);
    v8bf a0 = cvt8(x00, x01), a1 = cvt8(x10, x11);
#pragma unroll
    for (int j = 0; j < 8; ++j) {
      v8bf b = *(const v8bf*)(bp + (size_t)j * 16 * 1024 + k);
      acc[0][j] = mfma16(a0, b, acc[0][j]);
      acc[1][j] = mfma16(a1, b, acc[1][j]);
    }
  }
  const int cm = lc << 2, cn = lr;
#pragma unroll
  for (int f = 0; f < 2; ++f)
#pragma unroll
    for (int j = 0; j < 8; ++j) {
      int n = n0 + j * 16 + cn;
      float bias = bt1[n];
#pragma unroll
      for (int r = 0; r < 4; ++r) {
        int m = m0 + f * 16 + cm + r;
        xc[((size_t)m * 512 + t) * 2048 + n] = (__bf16)(acc[f][j][r] + bias);
      }
    }
}

// ---- act staging: issue (mixed fast/slow) + commit (swizzled LDS) -----------
template <int K>
__device__ inline void stage_issue(f32x4* v, const __bf16* fastb, const __bf16* slowb,
                                   unsigned sel, int tid) {
  constexpr int KC = K / 8;
#pragma unroll
  for (int i = 0; i < K / 128; ++i) {
    int idx = tid + i * 256;
    int row = idx / KC, kc = idx % KC;
    int slot = (K == 2048) ? (kc >> 3) : (kc >> 2);
    if ((sel >> slot) & 1u) {
      const __bf16* p = fastb + (size_t)row * K + kc * 8;
      asm volatile("global_load_dwordx4 %0, %1, off sc0" : "=v"(v[i]) : "v"(p));
    } else {
      const __bf16* p = slowb + (size_t)row * K + kc * 8;
      asm volatile("global_load_dwordx4 %0, %1, off sc0 sc1" : "=v"(v[i]) : "v"(p));
    }
  }
}
template <int K>
__device__ inline void stage_commit(char* lds, f32x4* v, int tid) {
  constexpr int KC = K / 8;
#pragma unroll
  for (int i = 0; i < K / 128; ++i) {
    int idx = tid + i * 256;
    int row = idx / KC, kc = idx % KC;
    unsigned byte = ((unsigned)(row * K + kc * 8) * 2) ^ ((unsigned)(row & 7) << 4);
    *(f32x4*)(lds + byte) = v[i];
  }
  __syncthreads();
}

// ---- weight ring GEMM body (ring pre-issued by caller) ----------------------
template <int KIT, int PFD, int KS>
__device__ inline f32x4 ring_run(const char* ldsa, int k0, const __bf16* wtb,
                                 f32x4* rw, int lane) {
  const int lr = lane & 15, lc = lane >> 4;
  f32x4 acc = {0.f, 0.f, 0.f, 0.f};
#pragma unroll
  for (int it = 0; it < KIT; ++it) {
    vwait_n((KIT - 1 - it) < (PFD - 1) ? (KIT - 1 - it) : (PFD - 1));
    v8bf b = as8(rw[it % PFD]);
    if (it + PFD < KIT) CLOADP(rw[it % PFD], wtb, (it + PFD) * 64);
    int k = k0 + it * 32 + lc * 8;
    unsigned byte = ((unsigned)(lr * KS + k) * 2) ^ ((unsigned)(lr & 7) << 4);
    v8bf a = *(const v8bf*)(ldsa + byte);
    acc = mfma16(a, b, acc);
  }
  return acc;
}
// ---- LDS act + LDS weights ([kb][32][8] layout) -----------------------------
template <int KIT, int KS>
__device__ inline f32x4 gemm_aa(const char* ldsa, int k0,
                                const char* ldsw, int col, int lane) {
  const int lr = lane & 15, lc = lane >> 4;
  f32x4 acc = {0.f, 0.f, 0.f, 0.f};
#pragma unroll
  for (int it = 0; it < KIT; ++it) {
    int k = k0 + it * 32 + lc * 8;
    unsigned abyte = ((unsigned)(lr * KS + k) * 2) ^ ((unsigned)(lr & 7) << 4);
    v8bf a = *(const v8bf*)(ldsa + abyte);
    v8bf b = *(const v8bf*)(ldsw + (size_t)((it * 4 + lc) * 32 + col) * 16);
    acc = mfma16(a, b, acc);
  }
  return acc;
}

// ---------------- persistent recurrence --------------------------------------
__global__ __launch_bounds__(256, 1) void recurrent_kernel(
    const __bf16* __restrict__ wWi1, const __bf16* __restrict__ wWi2,
    const __bf16* __restrict__ wWt1s, const __bf16* __restrict__ wWt2,
    const __bf16* __restrict__ wWt3, const __bf16* __restrict__ x0bf,
    __bf16* sbf, __bf16* sbfS, __bf16* z1, __bf16* z1S,
    __bf16* z2, __bf16* z2S,
    const float* __restrict__ bi1, const float* __restrict__ bi2,
    const float* __restrict__ bt2, const float* __restrict__ bt3,
    float* __restrict__ out, unsigned* __restrict__ flags) {
  __shared__ alignas(16) char actbuf[65536];   // [16][K<=2048] swizzled acts
  __shared__ alignas(16) char wt3buf[32768];   // Wt3 slice, k 0..512
  __shared__ float red[512];
  __shared__ unsigned s_sel;
  __shared__ int s_dead;
  const int bid = blockIdx.x;
  const int g = bid & 7, s = bid >> 3;
  const int tid = threadIdx.x, wid = tid >> 6, lane = tid & 63;
  const int lr = lane & 15, lc = lane >> 4;
  const int cm = lc << 2, cn = lr;
  const int wn = wid & 1, wk = wid >> 1;
  const int b0 = g * 16;

  unsigned xr;
  asm volatile("s_getreg_b32 %0, hwreg(HW_REG_XCC_ID)" : "=s"(xr));
  const int myxcd = (int)(xr & 7u);
  if (tid == 0) s_dead = 0;

  unsigned* fAf = flags + g * 96;          // fast flags
  unsigned* fBf = fAf + 32;
  unsigned* fCf = fAf + 64;
  unsigned* fAs = flags + 768 + g * 96;    // slow flags
  unsigned* fBs = fAs + 32;
  unsigned* fCs = fAs + 64;
  __bf16* sbf_f = sbf + (size_t)g * 16 * 1024;
  __bf16* sbf_s = sbfS + (size_t)g * 16 * 1024;
  __bf16* z1_f = z1 + (size_t)g * 16 * 2048;
  __bf16* z1_s = z1S + (size_t)g * 16 * 2048;
  __bf16* z2_f = z2 + (size_t)g * 16 * 1024;
  __bf16* z2_s = z2S + (size_t)g * 16 * 1024;
  const __bf16* xc = (const __bf16*)out;   // plain reads (pre-launch kernel)

  // stage Wt3 slice (cols s*32..+32, k<512) -> wt3buf [kb=64][32][8]
  {
    const __bf16* wg = wWt3 + (size_t)s * 32 * 1024;
    for (int idx = tid; idx < 2048; idx += 256) {
      int kb = idx >> 5, c = idx & 31;
      *(f32x4*)(wt3buf + (size_t)idx * 16) = *(const f32x4*)(wg + (size_t)c * 1024 + kb * 8);
    }
  }

  const int nBC = s * 32 + wn * 16 + cn;
  const int nA = s * 64 + wid * 16 + cn;
  const float bB = bt2[nBC], bC = bt3[nBC];
  const float bI1 = bi1[nBC], bI2 = bi2[nBC];
  constexpr int PFD = 12;
  f32x4 rw[PFD];

  // ---- init-B: h0 = silu(x0 @ Wi1^T + bi1) -> z2 (x0 plainly visible) ----
  {
    f32x4 sv[8];
    stage_issue<1024>(sv, x0bf + (size_t)b0 * 1024, x0bf + (size_t)b0 * 1024,
                      0xFFFFFFFFu, tid);
    const __bf16* wtb = wWi1 + (size_t)(s * 32 + wn * 16 + lr) * 1024 + wk * 512 + lc * 8;
#pragma unroll
    for (int j = 0; j < PFD; ++j) CLOADP(rw[j], wtb, j * 64);
    vwait<PFD>();
    stage_commit<1024>(actbuf, sv, tid);
    f32x4 acc = ring_run<16, PFD, 1024>(actbuf, wk * 512, wtb, rw, lane);
    if (wk) {
#pragma unroll
      for (int r = 0; r < 4; ++r) red[wn * 256 + (cm + r) * 16 + cn] = acc[r];
    }
    __syncthreads();
    if (!wk) {
#pragma unroll
      for (int r = 0; r < 4; ++r) {
        float v = acc[r] + red[wn * 256 + (cm + r) * 16 + cn] + bI1;
        st16d(z2_f + (size_t)(cm + r) * 1024 + nBC,
              z2_s + (size_t)(cm + r) * 1024 + nBC, silu_f(v));
      }
    }
    release_dual(fBf, fBs, s, (1u << 3) | (unsigned)myxcd);
  }
  // ---- init-C: s0 = h0 @ Wi2^T + bi2 -> out[:,0,:], sbf ----
  {
    unsigned sel = poll_sel(fBf, fBs, 1u, myxcd, &s_sel, &s_dead);
    f32x4 sv[8];
    stage_issue<1024>(sv, z2_f, z2_s, sel, tid);
    const __bf16* wtb = wWi2 + (size_t)(s * 32 + wn * 16 + lr) * 1024 + wk * 512 + lc * 8;
#pragma unroll
    for (int j = 0; j < PFD; ++j) CLOADP(rw[j], wtb, j * 64);
    vwait<PFD>();
    stage_commit<1024>(actbuf, sv, tid);
    f32x4 acc = ring_run<16, PFD, 1024>(actbuf, wk * 512, wtb, rw, lane);
    if (wk) {
#pragma unroll
      for (int r = 0; r < 4; ++r) red[wn * 256 + (cm + r) * 16 + cn] = acc[r];
    }
    __syncthreads();
    if (!wk) {
#pragma unroll
      for (int r = 0; r < 4; ++r) {
        float v = acc[r] + red[wn * 256 + (cm + r) * 16 + cn] + bI2;
        out[(size_t)(b0 + cm + r) * 524288 + nBC] = v;
        st16d(sbf_f + (size_t)(cm + r) * 1024 + nBC,
              sbf_s + (size_t)(cm + r) * 1024 + nBC, v);
      }
    }
    release_dual(fCf, fCs, s, (1u << 3) | (unsigned)myxcd);
  }

  for (int t = 1; t < 512; ++t) {
    // ---- A: z1 = silu(s_prev @ Wt1s^T + xc[t]) ----
    {
      unsigned sel = poll_sel(fCf, fCs, (unsigned)t, myxcd, &s_sel, &s_dead);
      f32x4 sv[8];
      stage_issue<1024>(sv, sbf_f, sbf_s, sel, tid);
      unsigned xcu[4];
#pragma unroll
      for (int r = 0; r < 4; ++r) {
        const __bf16* p = xc + ((size_t)(b0 + cm + r) * 512 + t) * 2048 + nA;
        asm volatile("global_load_ushort %0, %1, off" : "=v"(xcu[r]) : "v"(p));
      }
      const __bf16* wtb = wWt1s + (size_t)(s * 64 + wid * 16 + lr) * 1024 + lc * 8;
#pragma unroll
      for (int j = 0; j < PFD; ++j) CLOADP(rw[j], wtb, j * 64);
      vwait<PFD>();  // retires acts + xcu
      stage_commit<1024>(actbuf, sv, tid);
      f32x4 acc = ring_run<32, PFD, 1024>(actbuf, 0, wtb, rw, lane);
#pragma unroll
      for (int r = 0; r < 4; ++r) {
        float xv = __uint_as_float(xcu[r] << 16);
        st16d(z1_f + (size_t)(cm + r) * 2048 + nA,
              z1_s + (size_t)(cm + r) * 2048 + nA, silu_f(acc[r] + xv));
      }
      release_dual(fAf, fAs, s, ((unsigned)t << 3) | (unsigned)myxcd);
    }
    // ---- B: z2 = silu(z1 @ Wt2^T + bt2) ----
    {
      unsigned sel = poll_sel(fAf, fAs, (unsigned)t, myxcd, &s_sel, &s_dead);
      f32x4 sv[16];
      stage_issue<2048>(sv, z1_f, z1_s, sel, tid);
      const __bf16* wtb = wWt2 + (size_t)(s * 32 + wn * 16 + lr) * 2048 + wk * 1024 + lc * 8;
#pragma unroll
      for (int j = 0; j < PFD; ++j) CLOADP(rw[j], wtb, j * 64);
      vwait<PFD>();
      stage_commit<2048>(actbuf, sv, tid);
      f32x4 acc = ring_run<32, PFD, 2048>(actbuf, wk * 1024, wtb, rw, lane);
      if (wk) {
#pragma unroll
        for (int r = 0; r < 4; ++r) red[wn * 256 + (cm + r) * 16 + cn] = acc[r];
      }
      __syncthreads();
      if (!wk) {
#pragma unroll
        for (int r = 0; r < 4; ++r) {
          float v = acc[r] + red[wn * 256 + (cm + r) * 16 + cn] + bB;
          st16d(z2_f + (size_t)(cm + r) * 1024 + nBC,
                z2_s + (size_t)(cm + r) * 1024 + nBC, silu_f(v));
        }
      }
      release_dual(fBf, fBs, s, ((unsigned)(t + 1) << 3) | (unsigned)myxcd);
    }
    // ---- C: s = z2 @ Wt3^T + bt3 -> out, sbf ----
    {
      unsigned sel = poll_sel(fBf, fBs, (unsigned)(t + 1), myxcd, &s_sel, &s_dead);
      f32x4 sv[8];
      stage_issue<1024>(sv, z2_f, z2_s, sel, tid);
      f32x4 acc;
      if (wk) {
        const __bf16* wtb = wWt3 + (size_t)(s * 32 + wn * 16 + lr) * 1024 + 512 + lc * 8;
#pragma unroll
        for (int j = 0; j < PFD; ++j) CLOADP(rw[j], wtb, j * 64);
        vwait<PFD>();
        stage_commit<1024>(actbuf, sv, tid);
        acc = ring_run<16, PFD, 1024>(actbuf, 512, wtb, rw, lane);
#pragma unroll
        for (int r = 0; r < 4; ++r) red[wn * 256 + (cm + r) * 16 + cn] = acc[r];
      } else {
        vwait<0>();
        stage_commit<1024>(actbuf, sv, tid);
        acc = gemm_aa<16, 1024>(actbuf, 0, wt3buf, wn * 16 + lr, lane);
      }
      __syncthreads();
      if (!wk) {
#pragma unroll
        for (int r = 0; r < 4; ++r) {
          float v = acc[r] + red[wn * 256 + (cm + r) * 16 + cn] + bC;
          out[(size_t)(b0 + cm + r) * 524288 + (size_t)t * 1024 + nBC] = v;
          st16d(sbf_f + (size_t)(cm + r) * 1024 + nBC,
                sbf_s + (size_t)(cm + r) * 1024 + nBC, v);
        }
      }
      release_dual(fCf, fCs, s, ((unsigned)(t + 1) << 3) | (unsigned)myxcd);
    }
  }
}

// ---------------- host launcher ----------------------------------------------
extern "C" void kernel_launch(void* const* d_in, const int* in_sizes, int n_in,
                              void* d_out, int out_size, void* d_ws, size_t ws_size,
                              hipStream_t stream) {
  (void)in_sizes; (void)n_in; (void)out_size; (void)ws_size;
  const float* past = (const float*)d_in[0];
  const float* Wi1 = (const float*)d_in[1];
  const float* bi1 = (const float*)d_in[2];
  const float* Wi2 = (const float*)d_in[3];
  const float* bi2 = (const float*)d_in[4];
  const float* Wt1 = (const float*)d_in[5];
  const float* bt1 = (const float*)d_in[6];
  const float* Wt2 = (const float*)d_in[7];
  const float* bt2 = (const float*)d_in[8];
  const float* Wt3 = (const float*)d_in[9];
  const float* bt3 = (const float*)d_in[10];
  float* out = (float*)d_out;

  char* ws = (char*)d_ws;
  size_t off = 0;
  unsigned* flags = (unsigned*)(ws + off); off += 8192;
  __bf16* wWi1 = (__bf16*)(ws + off);  off += (size_t)1024 * 1024 * 2;
  __bf16* wWi2 = (__bf16*)(ws + off);  off += (size_t)1024 * 1024 * 2;
  __bf16* wWt1s = (__bf16*)(ws + off); off += (size_t)2048 * 1024 * 2;
  __bf16* wWt1x = (__bf16*)(ws + off); off += (size_t)2048 * 1024 * 2;
  __bf16* wWt2 = (__bf16*)(ws + off);  off += (size_t)1024 * 2048 * 2;
  __bf16* wWt3 = (__bf16*)(ws + off);  off += (size_t)1024 * 1024 * 2;
  __bf16* x0bf = (__bf16*)(ws + off);  off += (size_t)128 * 1024 * 2;
  __bf16* sbf = (__bf16*)(ws + off);   off += (size_t)128 * 1024 * 2;
  __bf16* sbfS = (__bf16*)(ws + off);  off += (size_t)128 * 1024 * 2;
  __bf16* z1 = (__bf16*)(ws + off);    off += (size_t)128 * 2048 * 2;
  __bf16* z1S = (__bf16*)(ws + off);   off += (size_t)128 * 2048 * 2;
  __bf16* z2 = (__bf16*)(ws + off);    off += (size_t)128 * 1024 * 2;
  __bf16* z2S = (__bf16*)(ws + off);   off += (size_t)128 * 1024 * 2;

  hipMemsetAsync(flags, 0, 8192, stream);

  auto cvt = [&](const float* s, __bf16* d, int rows, int cols, int log2c,
                 int sstride, int soff) {
    int total8 = rows * cols / 8;
    cvt_kernel<<<dim3((total8 + 255) / 256), dim3(256), 0, stream>>>(
        s, d, total8, log2c, sstride, soff);
  };
  cvt(Wi1, wWi1, 1024, 1024, 10, 1024, 0);
  cvt(Wi2, wWi2, 1024, 1024, 10, 1024, 0);
  cvt(Wt1, wWt1s, 2048, 1024, 10, 2048, 0);
  cvt(Wt1, wWt1x, 2048, 1024, 10, 2048, 1024);
  cvt(Wt2, wWt2, 1024, 2048, 11, 2048, 0);
  cvt(Wt3, wWt3, 1024, 1024, 10, 1024, 0);
  cvt(past, x0bf, 128, 1024, 10, 512 * 1024, 0);

  xc_gemm_kernel<<<dim3(4, 2, 511), dim3(512), 0, stream>>>(
      past, wWt1x, bt1, (__bf16*)d_out);

  recurrent_kernel<<<dim3(256), dim3(256), 0, stream>>>(
      wWi1, wWi2, wWt1s, wWt2, wWt3, x0bf,
      sbf, sbfS, z1, z1S, z2, z2S,
      bi1, bi2, bt2, bt3, out, flags);
}